// Round 12
// baseline (353.240 us; speedup 1.0000x reference)
//
#include <hip/hip_runtime.h>
#include <hip/hip_fp16.h>

#define N_NODES 100000
#define N_EDGES 1600000
#define IN_F 32
#define HID 128
#define BSHIFT 9
#define BSIZE 512
#define NBUCK 196       // ceil(100000/512)
#define EPB 8192        // edges per bucket-phase block
#define NBB 196         // ceil(E/EPB)

typedef _Float16 half8 __attribute__((ext_vector_type(8)));
typedef float floatx4 __attribute__((ext_vector_type(4)));

static __device__ __forceinline__ void pack2(_Float16* dst, float a, float b) {
    union { _Float16 h[2]; unsigned u; } p;
    p.h[0] = (_Float16)a; p.h[1] = (_Float16)b;
    *(unsigned*)dst = p.u;
}

// ---------------- CSR build (bucketed, no global per-node atomics) ----------------

__global__ __launch_bounds__(256) void k_bcount(const int* __restrict__ dst,
                                                int* __restrict__ bcnt) {
    __shared__ int hist[256];
    hist[threadIdx.x] = 0;
    __syncthreads();
    const int e0 = blockIdx.x * EPB;
#pragma unroll 4
    for (int k = 0; k < 32; ++k) {
        int e = e0 + k * 256 + threadIdx.x;
        if (e < N_EDGES) atomicAdd(&hist[dst[e] >> BSHIFT], 1);
    }
    __syncthreads();
    int c = hist[threadIdx.x];
    if (c > 0) atomicAdd(&bcnt[threadIdx.x], c);
}

__global__ __launch_bounds__(256) void k_bscan(const int* __restrict__ bcnt,
                                               int* __restrict__ bbase,
                                               int* __restrict__ bcur) {
    __shared__ int s[256];
    int v = (threadIdx.x < NBUCK) ? bcnt[threadIdx.x] : 0;
    s[threadIdx.x] = v;
    __syncthreads();
    for (int off = 1; off < 256; off <<= 1) {
        int t = (threadIdx.x >= off) ? s[threadIdx.x - off] : 0;
        __syncthreads();
        s[threadIdx.x] += t;
        __syncthreads();
    }
    if (threadIdx.x < NBUCK) {
        int ex = s[threadIdx.x] - v;
        bbase[threadIdx.x] = ex;
        bcur[threadIdx.x]  = ex;
    }
    if (threadIdx.x == 0) bbase[NBUCK] = N_EDGES;
}

__global__ __launch_bounds__(256) void k_bucket(const int* __restrict__ src,
                                                const int* __restrict__ dst,
                                                int* __restrict__ bcur,
                                                unsigned* __restrict__ rec) {
    __shared__ int hist[256];
    __shared__ int lbase[256];
    const int e0 = blockIdx.x * EPB;
    hist[threadIdx.x] = 0;
    __syncthreads();

    unsigned rk[32]; short bk[32];
#pragma unroll
    for (int k = 0; k < 32; ++k) {
        int e = e0 + k * 256 + threadIdx.x;
        if (e < N_EDGES) {
            int d = dst[e];
            int b = d >> BSHIFT;
            bk[k] = (short)b;
            rk[k] = ((unsigned)src[e] << BSHIFT) | (unsigned)(d & (BSIZE - 1));
            atomicAdd(&hist[b], 1);
        } else bk[k] = -1;
    }
    __syncthreads();
    int c = hist[threadIdx.x];
    lbase[threadIdx.x] = (c > 0) ? atomicAdd(&bcur[threadIdx.x], c) : 0;
    __syncthreads();
    hist[threadIdx.x] = 0;   // reuse as local running offset
    __syncthreads();
#pragma unroll
    for (int k = 0; k < 32; ++k) {
        if (bk[k] >= 0) {
            int off = atomicAdd(&hist[bk[k]], 1);
            rec[lbase[bk[k]] + off] = rk[k];
        }
    }
}

// per bucket: LDS degree count + scan -> ideg/cursor + col scatter + fused prescale
__global__ __launch_bounds__(256) void k_fill3p(const unsigned* __restrict__ rec,
                                                const int* __restrict__ bbase,
                                                const float2* __restrict__ x,
                                                int* __restrict__ ideg,
                                                int* __restrict__ cursor,
                                                int* __restrict__ col,
                                                __half2* __restrict__ t1h) {
    __shared__ int lcnt[BSIZE];
    __shared__ int lcur[BSIZE];
    __shared__ int s[256];
    const int b = blockIdx.x;
    const int n0 = b << BSHIFT;
    const int rbeg = bbase[b];
    const int rend = bbase[b + 1];

    lcnt[threadIdx.x] = 0;
    lcnt[threadIdx.x + 256] = 0;
    __syncthreads();
    for (int i = rbeg + threadIdx.x; i < rend; i += 256)
        atomicAdd(&lcnt[rec[i] & (BSIZE - 1)], 1);
    __syncthreads();

    int a0 = lcnt[2 * threadIdx.x], a1 = lcnt[2 * threadIdx.x + 1];
    int pv = a0 + a1;
    s[threadIdx.x] = pv;
    __syncthreads();
    for (int off = 1; off < 256; off <<= 1) {
        int t = (threadIdx.x >= off) ? s[threadIdx.x - off] : 0;
        __syncthreads();
        s[threadIdx.x] += t;
        __syncthreads();
    }
    int ex = s[threadIdx.x] - pv;
    lcur[2 * threadIdx.x]     = rbeg + ex;
    lcur[2 * threadIdx.x + 1] = rbeg + ex + a0;
    __syncthreads();

    for (int t = threadIdx.x; t < BSIZE; t += 256) {
        int n = n0 + t;
        if (n < N_NODES) {
            ideg[n]   = lcnt[t];
            cursor[n] = lcur[t];
        }
    }
    // fused prescale: t1 = x * dis for this bucket's nodes (lcnt stable)
    const int cnt = (n0 + BSIZE <= N_NODES) ? BSIZE : (N_NODES - n0);
    for (int t = threadIdx.x; t < cnt * 16; t += 256) {
        int ln = t >> 4;
        float dis = rsqrtf(1.0f + (float)lcnt[ln]);
        float2 v = x[(size_t)n0 * 16 + t];
        t1h[(size_t)n0 * 16 + t] = __floats2half2_rn(v.x * dis, v.y * dis);
    }
    __syncthreads();
    for (int i = rbeg + threadIdx.x; i < rend; i += 256) {
        unsigned r = rec[i];
        int slot = atomicAdd(&lcur[r & (BSIZE - 1)], 1);
        col[slot] = (int)(r >> BSHIFT);
    }
}

// ---------------- fused L1: 32-dim gather (v2 loop) + xform1 (z@W1+b1, relu) ----------------
// 16 slots x 4 feat-lanes. After xor-butterfly, ALL lanes hold reduced acc; 3 extra
// shuffles give each lane all 32 z-values; per-lane dot computes outputs j=lane, lane+64.

__global__ __launch_bounds__(256) void k_g32_xf1(
    const int* __restrict__ cursor, const int* __restrict__ ideg,
    const int* __restrict__ col, const _Float16* __restrict__ T,
    const float* __restrict__ W1, const float* __restrict__ b1,
    _Float16* __restrict__ H) {
    __shared__ __half2 W1p[2048];   // [k2][j]: (k=2k2,2k2+1) x j=0..127, 8KB
    for (int idx = threadIdx.x; idx < 2048; idx += 256) {
        int k2 = idx >> 7, j = idx & 127;
        W1p[idx] = __floats2half2_rn(W1[(2 * k2) * HID + j], W1[(2 * k2 + 1) * HID + j]);
    }
    __syncthreads();

    const int lane = threadIdx.x & 63;
    const int slot = lane >> 2;
    const int fl   = lane & 3;
    const int wid  = blockIdx.x * 4 + (threadIdx.x >> 6);
    const int wstride = gridDim.x * 4;
    const float bj0 = b1[lane];
    const float bj1 = b1[lane + 64];

    for (int node = wid; node < N_NODES; node += wstride) {
        int begin = cursor[node];
        int d     = ideg[node];
        int end   = begin + d;
        float acc[8];
        if (slot == 0) {
            half8 v = *(const half8*)(T + (size_t)node * IN_F + fl * 8);
#pragma unroll
            for (int i = 0; i < 8; ++i) acc[i] = (float)v[i];
        } else {
#pragma unroll
            for (int i = 0; i < 8; ++i) acc[i] = 0.f;
        }
        for (int e = begin; e < end; e += 16) {   // v2 loop (r9-proven)
            int ee = e + slot;
            if (ee < end) {
                int s = col[ee];
                half8 v = *(const half8*)(T + (size_t)s * IN_F + fl * 8);
#pragma unroll
                for (int i = 0; i < 8; ++i) acc[i] += (float)v[i];
            }
        }
#pragma unroll
        for (int m = 4; m < 64; m <<= 1)
#pragma unroll
            for (int i = 0; i < 8; ++i) acc[i] += __shfl_xor(acc[i], m, 64);

        // all lanes now hold the fl-group sums; scale and broadcast across fl
        float dis = rsqrtf(1.0f + (float)d);
        float zz[4][8];
#pragma unroll
        for (int i = 0; i < 8; ++i) zz[0][i] = acc[i] * dis;
#pragma unroll
        for (int i = 0; i < 8; ++i) zz[1][i] = __shfl_xor(zz[0][i], 1, 64);
#pragma unroll
        for (int i = 0; i < 8; ++i) zz[2][i] = __shfl_xor(zz[0][i], 2, 64);
#pragma unroll
        for (int i = 0; i < 8; ++i) zz[3][i] = __shfl_xor(zz[0][i], 3, 64);

        float s0 = 0.f, s1 = 0.f;
#pragma unroll
        for (int m = 0; m < 4; ++m) {
            int f = fl ^ m;   // logical feature-block of zz[m]
#pragma unroll
            for (int i2 = 0; i2 < 4; ++i2) {
                float2 w0 = __half22float2(W1p[(f * 4 + i2) * 128 + lane]);
                float2 w1 = __half22float2(W1p[(f * 4 + i2) * 128 + lane + 64]);
                s0 += zz[m][2 * i2] * w0.x + zz[m][2 * i2 + 1] * w0.y;
                s1 += zz[m][2 * i2] * w1.x + zz[m][2 * i2 + 1] * w1.y;
            }
        }
        float v0 = s0 + bj0, v1 = s1 + bj1;
        H[(size_t)node * HID + lane]      = (_Float16)(v0 > 0.f ? v0 : 0.f);
        H[(size_t)node * HID + lane + 64] = (_Float16)(v1 > 0.f ? v1 : 0.f);
    }
}

// ---------------- fused L2/L3: 128-dim gather (v2 loop) + epilogue + xform3 ----------------
// H2 row = relu(agg*dis + b2) -> LDS; per-lane dot with W3 -> T3 = (H2@W3)*dis.

__global__ __launch_bounds__(256) void k_g128_xf3(
    const int* __restrict__ cursor, const int* __restrict__ ideg,
    const int* __restrict__ col, const _Float16* __restrict__ T,
    const float* __restrict__ b2, const float* __restrict__ W3,
    _Float16* __restrict__ T3) {
    __shared__ __half2 W3p[2048];    // [k2][j]: (k=2k2,2k2+1) x j=0..31, 8KB
    __shared__ float hrow[4][HID];   // per-wave H2 row
    for (int idx = threadIdx.x; idx < 2048; idx += 256) {
        int k2 = idx >> 5, j = idx & 31;
        W3p[idx] = __floats2half2_rn(W3[(2 * k2) * IN_F + j], W3[(2 * k2 + 1) * IN_F + j]);
    }
    __syncthreads();

    const int lane = threadIdx.x & 63;
    const int slot = lane >> 4;
    const int fl   = lane & 15;
    const int wave = threadIdx.x >> 6;
    const int wid  = blockIdx.x * 4 + wave;
    const int wstride = gridDim.x * 4;
    const int jcol  = lane & 31;
    const int khalf = (lane >> 5) * 32;   // k2 range base: 0 or 32

    float4 bb0 = *(const float4*)(b2 + fl * 8);
    float4 bb1 = *(const float4*)(b2 + fl * 8 + 4);
    float bias[8] = {bb0.x, bb0.y, bb0.z, bb0.w, bb1.x, bb1.y, bb1.z, bb1.w};

    for (int node = wid; node < N_NODES; node += wstride) {
        int begin = cursor[node];
        int d     = ideg[node];
        int end   = begin + d;
        float acc[8];
        if (slot == 0) {
            half8 v = *(const half8*)(T + (size_t)node * HID + fl * 8);
#pragma unroll
            for (int i = 0; i < 8; ++i) acc[i] = (float)v[i];
        } else {
#pragma unroll
            for (int i = 0; i < 8; ++i) acc[i] = 0.f;
        }
        for (int e = begin; e < end; e += 8) {    // v2 loop (r9-proven)
            int ee0 = e + slot;
            int ee1 = e + 4 + slot;
            if (ee1 < end) {
                int s0 = col[ee0];
                int s1 = col[ee1];
                half8 v0 = *(const half8*)(T + (size_t)s0 * HID + fl * 8);
                half8 v1 = *(const half8*)(T + (size_t)s1 * HID + fl * 8);
#pragma unroll
                for (int i = 0; i < 8; ++i) acc[i] += (float)v0[i] + (float)v1[i];
            } else if (ee0 < end) {
                int s0 = col[ee0];
                half8 v0 = *(const half8*)(T + (size_t)s0 * HID + fl * 8);
#pragma unroll
                for (int i = 0; i < 8; ++i) acc[i] += (float)v0[i];
            }
        }
#pragma unroll
        for (int m = 16; m < 64; m <<= 1)
#pragma unroll
            for (int i = 0; i < 8; ++i) acc[i] += __shfl_xor(acc[i], m, 64);

        float dis = rsqrtf(1.0f + (float)d);
        if (slot == 0) {   // 16 lanes write the full 128-float H2 row
#pragma unroll
            for (int i = 0; i < 8; ++i) {
                float v = acc[i] * dis + bias[i];
                hrow[wave][fl * 8 + i] = v > 0.f ? v : 0.f;
            }
        }
        // per-wave LDS RAW: same-wave ordering + compiler waitcnt (no barrier needed)
        float s = 0.f;
#pragma unroll 8
        for (int k2 = 0; k2 < 32; ++k2) {
            float2 h2 = *(const float2*)&hrow[wave][(khalf + k2) * 2];
            float2 wf = __half22float2(W3p[(khalf + k2) * 32 + jcol]);
            s += h2.x * wf.x + h2.y * wf.y;
        }
        s += __shfl_xor(s, 32, 64);
        if (lane < 32)
            T3[(size_t)node * IN_F + jcol] = (_Float16)(s * dis);
    }
}

// ---------------- final 32-dim gather (v2 loop): out = relu(acc*dis + b3), fp32 ----------------

__global__ __launch_bounds__(256) void k_g32fin(
    const int* __restrict__ cursor, const int* __restrict__ ideg,
    const int* __restrict__ col, const _Float16* __restrict__ T,
    const float* __restrict__ b, float* __restrict__ OUT) {
    const int lane = threadIdx.x & 63;
    const int slot = lane >> 2;
    const int fl   = lane & 3;
    const int wid  = blockIdx.x * 4 + (threadIdx.x >> 6);
    const int wstride = gridDim.x * 4;

    float4 bb0 = *(const float4*)(b + fl * 8);
    float4 bb1 = *(const float4*)(b + fl * 8 + 4);
    float bias[8] = {bb0.x, bb0.y, bb0.z, bb0.w, bb1.x, bb1.y, bb1.z, bb1.w};

    for (int node = wid; node < N_NODES; node += wstride) {
        int begin = cursor[node];
        int d     = ideg[node];
        int end   = begin + d;
        float acc[8];
        if (slot == 0) {
            half8 v = *(const half8*)(T + (size_t)node * IN_F + fl * 8);
#pragma unroll
            for (int i = 0; i < 8; ++i) acc[i] = (float)v[i];
        } else {
#pragma unroll
            for (int i = 0; i < 8; ++i) acc[i] = 0.f;
        }
        for (int e = begin; e < end; e += 16) {
            int ee = e + slot;
            if (ee < end) {
                int s = col[ee];
                half8 v = *(const half8*)(T + (size_t)s * IN_F + fl * 8);
#pragma unroll
                for (int i = 0; i < 8; ++i) acc[i] += (float)v[i];
            }
        }
#pragma unroll
        for (int m = 4; m < 64; m <<= 1)
#pragma unroll
            for (int i = 0; i < 8; ++i) acc[i] += __shfl_xor(acc[i], m, 64);
        if (slot == 0) {
            float dis = rsqrtf(1.0f + (float)d);
            float o[8];
#pragma unroll
            for (int i = 0; i < 8; ++i) {
                float v = acc[i] * dis + bias[i];
                o[i] = v > 0.f ? v : 0.f;
            }
            float* op = OUT + (size_t)node * IN_F + fl * 8;
            *(float4*)op       = make_float4(o[0], o[1], o[2], o[3]);
            *(float4*)(op + 4) = make_float4(o[4], o[5], o[6], o[7]);
        }
    }
}

// ---------------- MFMA transform L2 (unchanged) ----------------

__global__ __launch_bounds__(256) void k_xform2_mfma(
    const _Float16* __restrict__ H, const float* __restrict__ W,
    const int* __restrict__ ideg, _Float16* __restrict__ T) {
    __shared__ _Float16 Wt[128 * 136];
    for (int idx = threadIdx.x; idx < 8192; idx += 256) {
        int n = idx & 127, k = (idx >> 7) * 2;
        pack2(&Wt[n * 136 + k], W[k * HID + n], W[(k + 1) * HID + n]);
    }
    __syncthreads();

    const int lane = threadIdx.x & 63;
    const int wave = threadIdx.x >> 6;
    const int m16 = lane & 15, quad = lane >> 4;
    const int row0 = blockIdx.x * 64 + wave * 16;
    if (row0 >= N_NODES) return;

    int arow = row0 + m16; if (arow >= N_NODES) arow = N_NODES - 1;
    const _Float16* hp = H + (size_t)arow * HID + quad * 8;
    half8 a[4];
#pragma unroll
    for (int kk = 0; kk < 4; ++kk) a[kk] = *(const half8*)(hp + kk * 32);

    floatx4 acc[8];
#pragma unroll
    for (int t = 0; t < 8; ++t) acc[t] = (floatx4){0.f, 0.f, 0.f, 0.f};
#pragma unroll
    for (int t = 0; t < 8; ++t) {
        const _Float16* wp = &Wt[(t * 16 + m16) * 136 + quad * 8];
#pragma unroll
        for (int kk = 0; kk < 4; ++kk) {
            half8 b = *(const half8*)(wp + kk * 32);
            acc[t] = __builtin_amdgcn_mfma_f32_16x16x32_f16(a[kk], b, acc[t], 0, 0, 0);
        }
    }
    float dis[4];
#pragma unroll
    for (int r = 0; r < 4; ++r) {
        int row = row0 + quad * 4 + r;
        dis[r] = (row < N_NODES) ? rsqrtf(1.0f + (float)ideg[row]) : 0.f;
    }
#pragma unroll
    for (int t = 0; t < 8; ++t) {
        int c = t * 16 + m16;
#pragma unroll
        for (int r = 0; r < 4; ++r) {
            int row = row0 + quad * 4 + r;
            if (row < N_NODES)
                T[(size_t)row * HID + c] = (_Float16)(acc[t][r] * dis[r]);
        }
    }
}

// ---------------- launch ----------------

extern "C" void kernel_launch(void* const* d_in, const int* in_sizes, int n_in,
                              void* d_out, int out_size, void* d_ws, size_t ws_size,
                              hipStream_t stream) {
    const float* x  = (const float*)d_in[0];
    const int*   ei = (const int*)d_in[1];
    const float* W1 = (const float*)d_in[2];
    const float* b1 = (const float*)d_in[3];
    const float* W2 = (const float*)d_in[4];
    const float* b2 = (const float*)d_in[5];
    const float* W3 = (const float*)d_in[6];
    const float* b3 = (const float*)d_in[7];
    float* out = (float*)d_out;

    const int* src = ei;             // edge_index[0]
    const int* dst = ei + N_EDGES;   // edge_index[1]

    // workspace layout (all offsets 16B-aligned)
    int*      ideg   = (int*)d_ws;                           // N (padded 102400)
    int*      cursor = ideg + 102400;                        // N
    int*      bcnt   = cursor + 102400;                      // 256
    int*      bbase  = bcnt + 256;                           // 256 (197 used)
    int*      bcur   = bbase + 256;                          // 256
    int*      col    = bcur + 256;                           // E
    unsigned* rec    = (unsigned*)(col + N_EDGES);           // E
    _Float16* t1h    = (_Float16*)(rec + N_EDGES);           // N*32 fp16 (L1 msgs)
    _Float16* H1h    = t1h + (size_t)N_NODES * IN_F;         // N*128 fp16
    _Float16* T2h    = H1h + (size_t)N_NODES * HID;          // N*128 fp16
    _Float16* T3h    = T2h + (size_t)N_NODES * HID;          // N*32 fp16

    // ---- CSR build + prescale (4 kernels + 1 memset) ----
    hipMemsetAsync(bcnt, 0, 256 * sizeof(int), stream);
    k_bcount<<<NBB, 256, 0, stream>>>(dst, bcnt);
    k_bscan<<<1, 256, 0, stream>>>(bcnt, bbase, bcur);
    k_bucket<<<NBB, 256, 0, stream>>>(src, dst, bcur, rec);
    k_fill3p<<<NBUCK, 256, 0, stream>>>(rec, bbase, (const float2*)x,
                                        ideg, cursor, col, (__half2*)t1h);

    // ---- layer 1: fused 32-dim gather + xform1 ----
    k_g32_xf1<<<2048, 256, 0, stream>>>(cursor, ideg, col, t1h, W1, b1, H1h);

    // ---- layer 2: MFMA transform, then fused 128-dim gather + xform3 ----
    k_xform2_mfma<<<(N_NODES + 63) / 64, 256, 0, stream>>>(H1h, W2, ideg, T2h);
    k_g128_xf3<<<2048, 256, 0, stream>>>(cursor, ideg, col, T2h, b2, W3, T3h);

    // ---- layer 3: final 32-dim gather ----
    k_g32fin<<<2048, 256, 0, stream>>>(cursor, ideg, col, T3h, b3, out);
}

// Round 13
// 342.301 us; speedup vs baseline: 1.0320x; 1.0320x over previous
//
#include <hip/hip_runtime.h>
#include <hip/hip_fp16.h>

#define N_NODES 100000
#define N_EDGES 1600000
#define IN_F 32
#define HID 128
#define BSHIFT 9
#define BSIZE 512
#define NBUCK 196       // ceil(100000/512)
#define EPB 8192        // edges per bucket-phase block
#define NBB 196         // ceil(E/EPB)

typedef _Float16 half8 __attribute__((ext_vector_type(8)));
typedef float floatx4 __attribute__((ext_vector_type(4)));

static __device__ __forceinline__ void pack2(_Float16* dst, float a, float b) {
    union { _Float16 h[2]; unsigned u; } p;
    p.h[0] = (_Float16)a; p.h[1] = (_Float16)b;
    *(unsigned*)dst = p.u;
}

// ---------------- CSR build (bucketed, no global per-node atomics) ----------------

__global__ __launch_bounds__(256) void k_bcount(const int* __restrict__ dst,
                                                int* __restrict__ bcnt) {
    __shared__ int hist[256];
    hist[threadIdx.x] = 0;
    __syncthreads();
    const int e0 = blockIdx.x * EPB;
#pragma unroll 4
    for (int k = 0; k < 32; ++k) {
        int e = e0 + k * 256 + threadIdx.x;
        if (e < N_EDGES) atomicAdd(&hist[dst[e] >> BSHIFT], 1);
    }
    __syncthreads();
    int c = hist[threadIdx.x];
    if (c > 0) atomicAdd(&bcnt[threadIdx.x], c);
}

__global__ __launch_bounds__(256) void k_bscan(const int* __restrict__ bcnt,
                                               int* __restrict__ bbase,
                                               int* __restrict__ bcur) {
    __shared__ int s[256];
    int v = (threadIdx.x < NBUCK) ? bcnt[threadIdx.x] : 0;
    s[threadIdx.x] = v;
    __syncthreads();
    for (int off = 1; off < 256; off <<= 1) {
        int t = (threadIdx.x >= off) ? s[threadIdx.x - off] : 0;
        __syncthreads();
        s[threadIdx.x] += t;
        __syncthreads();
    }
    if (threadIdx.x < NBUCK) {
        int ex = s[threadIdx.x] - v;
        bbase[threadIdx.x] = ex;
        bcur[threadIdx.x]  = ex;
    }
    if (threadIdx.x == 0) bbase[NBUCK] = N_EDGES;
}

__global__ __launch_bounds__(256) void k_bucket(const int* __restrict__ src,
                                                const int* __restrict__ dst,
                                                int* __restrict__ bcur,
                                                unsigned* __restrict__ rec) {
    __shared__ int hist[256];
    __shared__ int lbase[256];
    const int e0 = blockIdx.x * EPB;
    hist[threadIdx.x] = 0;
    __syncthreads();

    unsigned rk[32]; short bk[32];
#pragma unroll
    for (int k = 0; k < 32; ++k) {
        int e = e0 + k * 256 + threadIdx.x;
        if (e < N_EDGES) {
            int d = dst[e];
            int b = d >> BSHIFT;
            bk[k] = (short)b;
            rk[k] = ((unsigned)src[e] << BSHIFT) | (unsigned)(d & (BSIZE - 1));
            atomicAdd(&hist[b], 1);
        } else bk[k] = -1;
    }
    __syncthreads();
    int c = hist[threadIdx.x];
    lbase[threadIdx.x] = (c > 0) ? atomicAdd(&bcur[threadIdx.x], c) : 0;
    __syncthreads();
    hist[threadIdx.x] = 0;   // reuse as local running offset
    __syncthreads();
#pragma unroll
    for (int k = 0; k < 32; ++k) {
        if (bk[k] >= 0) {
            int off = atomicAdd(&hist[bk[k]], 1);
            rec[lbase[bk[k]] + off] = rk[k];
        }
    }
}

// per bucket: LDS degree count + scan -> ideg/cursor + col scatter + fused prescale
__global__ __launch_bounds__(256) void k_fill3p(const unsigned* __restrict__ rec,
                                                const int* __restrict__ bbase,
                                                const float2* __restrict__ x,
                                                int* __restrict__ ideg,
                                                int* __restrict__ cursor,
                                                int* __restrict__ col,
                                                __half2* __restrict__ t1h) {
    __shared__ int lcnt[BSIZE];
    __shared__ int lcur[BSIZE];
    __shared__ int s[256];
    const int b = blockIdx.x;
    const int n0 = b << BSHIFT;
    const int rbeg = bbase[b];
    const int rend = bbase[b + 1];

    lcnt[threadIdx.x] = 0;
    lcnt[threadIdx.x + 256] = 0;
    __syncthreads();
    for (int i = rbeg + threadIdx.x; i < rend; i += 256)
        atomicAdd(&lcnt[rec[i] & (BSIZE - 1)], 1);
    __syncthreads();

    int a0 = lcnt[2 * threadIdx.x], a1 = lcnt[2 * threadIdx.x + 1];
    int pv = a0 + a1;
    s[threadIdx.x] = pv;
    __syncthreads();
    for (int off = 1; off < 256; off <<= 1) {
        int t = (threadIdx.x >= off) ? s[threadIdx.x - off] : 0;
        __syncthreads();
        s[threadIdx.x] += t;
        __syncthreads();
    }
    int ex = s[threadIdx.x] - pv;
    lcur[2 * threadIdx.x]     = rbeg + ex;
    lcur[2 * threadIdx.x + 1] = rbeg + ex + a0;
    __syncthreads();

    for (int t = threadIdx.x; t < BSIZE; t += 256) {
        int n = n0 + t;
        if (n < N_NODES) {
            ideg[n]   = lcnt[t];
            cursor[n] = lcur[t];
        }
    }
    // fused prescale: t1 = x * dis for this bucket's nodes (lcnt stable)
    const int cnt = (n0 + BSIZE <= N_NODES) ? BSIZE : (N_NODES - n0);
    for (int t = threadIdx.x; t < cnt * 16; t += 256) {
        int ln = t >> 4;
        float dis = rsqrtf(1.0f + (float)lcnt[ln]);
        float2 v = x[(size_t)n0 * 16 + t];
        t1h[(size_t)n0 * 16 + t] = __floats2half2_rn(v.x * dis, v.y * dis);
    }
    __syncthreads();
    for (int i = rbeg + threadIdx.x; i < rend; i += 256) {
        unsigned r = rec[i];
        int slot = atomicAdd(&lcur[r & (BSIZE - 1)], 1);
        col[slot] = (int)(r >> BSHIFT);
    }
}

// ---------------- gathers (r9-proven v2 loops) ----------------

// pre: z = acc*dis, fp16 out. 16 slots x 4 feat-lanes.
__global__ __launch_bounds__(256) void k_gather32_pre(
    const int* __restrict__ cursor, const int* __restrict__ ideg,
    const int* __restrict__ col, const _Float16* __restrict__ T,
    _Float16* __restrict__ OUT) {
    const int lane = threadIdx.x & 63;
    const int slot = lane >> 2;
    const int fl   = lane & 3;
    const int wid  = blockIdx.x * 4 + (threadIdx.x >> 6);
    const int wstride = gridDim.x * 4;

    for (int node = wid; node < N_NODES; node += wstride) {
        int begin = cursor[node];
        int d     = ideg[node];
        int end   = begin + d;
        float acc[8];
        if (slot == 0) {
            half8 v = *(const half8*)(T + (size_t)node * IN_F + fl * 8);
#pragma unroll
            for (int i = 0; i < 8; ++i) acc[i] = (float)v[i];
        } else {
#pragma unroll
            for (int i = 0; i < 8; ++i) acc[i] = 0.f;
        }
        for (int e = begin; e < end; e += 16) {
            int ee = e + slot;
            if (ee < end) {
                int s = col[ee];
                half8 v = *(const half8*)(T + (size_t)s * IN_F + fl * 8);
#pragma unroll
                for (int i = 0; i < 8; ++i) acc[i] += (float)v[i];
            }
        }
#pragma unroll
        for (int m = 4; m < 64; m <<= 1)
#pragma unroll
            for (int i = 0; i < 8; ++i) acc[i] += __shfl_xor(acc[i], m, 64);
        if (slot == 0) {
            float dis = rsqrtf(1.0f + (float)d);
            half8 o;
#pragma unroll
            for (int i = 0; i < 8; ++i) o[i] = (_Float16)(acc[i] * dis);
            *(half8*)(OUT + (size_t)node * IN_F + fl * 8) = o;
        }
    }
}

// fin: out = relu(acc*dis + b), fp32 out
__global__ __launch_bounds__(256) void k_gather32_fin(
    const int* __restrict__ cursor, const int* __restrict__ ideg,
    const int* __restrict__ col, const _Float16* __restrict__ T,
    const float* __restrict__ b, float* __restrict__ OUT) {
    const int lane = threadIdx.x & 63;
    const int slot = lane >> 2;
    const int fl   = lane & 3;
    const int wid  = blockIdx.x * 4 + (threadIdx.x >> 6);
    const int wstride = gridDim.x * 4;

    float4 bb0 = *(const float4*)(b + fl * 8);
    float4 bb1 = *(const float4*)(b + fl * 8 + 4);
    float bias[8] = {bb0.x, bb0.y, bb0.z, bb0.w, bb1.x, bb1.y, bb1.z, bb1.w};

    for (int node = wid; node < N_NODES; node += wstride) {
        int begin = cursor[node];
        int d     = ideg[node];
        int end   = begin + d;
        float acc[8];
        if (slot == 0) {
            half8 v = *(const half8*)(T + (size_t)node * IN_F + fl * 8);
#pragma unroll
            for (int i = 0; i < 8; ++i) acc[i] = (float)v[i];
        } else {
#pragma unroll
            for (int i = 0; i < 8; ++i) acc[i] = 0.f;
        }
        for (int e = begin; e < end; e += 16) {
            int ee = e + slot;
            if (ee < end) {
                int s = col[ee];
                half8 v = *(const half8*)(T + (size_t)s * IN_F + fl * 8);
#pragma unroll
                for (int i = 0; i < 8; ++i) acc[i] += (float)v[i];
            }
        }
#pragma unroll
        for (int m = 4; m < 64; m <<= 1)
#pragma unroll
            for (int i = 0; i < 8; ++i) acc[i] += __shfl_xor(acc[i], m, 64);
        if (slot == 0) {
            float dis = rsqrtf(1.0f + (float)d);
            float o[8];
#pragma unroll
            for (int i = 0; i < 8; ++i) {
                float v = acc[i] * dis + bias[i];
                o[i] = v > 0.f ? v : 0.f;
            }
            float* op = OUT + (size_t)node * IN_F + fl * 8;
            *(float4*)op       = make_float4(o[0], o[1], o[2], o[3]);
            *(float4*)(op + 4) = make_float4(o[4], o[5], o[6], o[7]);
        }
    }
}

// 128-dim: 4 slots x 16 feat-lanes, x2 unroll; fp16 out = relu(acc*dis+b)
__global__ __launch_bounds__(256) void k_gather128(
    const int* __restrict__ cursor, const int* __restrict__ ideg,
    const int* __restrict__ col, const _Float16* __restrict__ T,
    const float* __restrict__ b, _Float16* __restrict__ OUT) {
    const int lane = threadIdx.x & 63;
    const int slot = lane >> 4;
    const int fl   = lane & 15;
    const int wid  = blockIdx.x * 4 + (threadIdx.x >> 6);
    const int wstride = gridDim.x * 4;

    float4 bb0 = *(const float4*)(b + fl * 8);
    float4 bb1 = *(const float4*)(b + fl * 8 + 4);
    float bias[8] = {bb0.x, bb0.y, bb0.z, bb0.w, bb1.x, bb1.y, bb1.z, bb1.w};

    for (int node = wid; node < N_NODES; node += wstride) {
        int begin = cursor[node];
        int d     = ideg[node];
        int end   = begin + d;
        float acc[8];
        if (slot == 0) {
            half8 v = *(const half8*)(T + (size_t)node * HID + fl * 8);
#pragma unroll
            for (int i = 0; i < 8; ++i) acc[i] = (float)v[i];
        } else {
#pragma unroll
            for (int i = 0; i < 8; ++i) acc[i] = 0.f;
        }
        for (int e = begin; e < end; e += 8) {
            int ee0 = e + slot;
            int ee1 = e + 4 + slot;
            if (ee1 < end) {
                int s0 = col[ee0];
                int s1 = col[ee1];
                half8 v0 = *(const half8*)(T + (size_t)s0 * HID + fl * 8);
                half8 v1 = *(const half8*)(T + (size_t)s1 * HID + fl * 8);
#pragma unroll
                for (int i = 0; i < 8; ++i) acc[i] += (float)v0[i] + (float)v1[i];
            } else if (ee0 < end) {
                int s0 = col[ee0];
                half8 v0 = *(const half8*)(T + (size_t)s0 * HID + fl * 8);
#pragma unroll
                for (int i = 0; i < 8; ++i) acc[i] += (float)v0[i];
            }
        }
#pragma unroll
        for (int m = 16; m < 64; m <<= 1)
#pragma unroll
            for (int i = 0; i < 8; ++i) acc[i] += __shfl_xor(acc[i], m, 64);
        if (slot == 0) {
            float dis = rsqrtf(1.0f + (float)d);
            half8 o;
#pragma unroll
            for (int i = 0; i < 8; ++i) {
                float v = acc[i] * dis + bias[i];
                o[i] = (_Float16)(v > 0.f ? v : 0.f);
            }
            *(half8*)(OUT + (size_t)node * HID + fl * 8) = o;
        }
    }
}

// ---------------- MFMA transforms (r9-proven) ----------------
// 16x16x32 layouts: A[m=lane&15][k=quad*8+j], B[k=quad*8+j][n=lane&15],
// D[row=quad*4+r][col=lane&15]. Block = 4 waves x 16 rows = 64 rows.

__global__ __launch_bounds__(256) void k_xform1_mfma(
    const _Float16* __restrict__ z, const float* __restrict__ W,
    const float* __restrict__ bias, _Float16* __restrict__ Hh) {
    __shared__ _Float16 Wt[128 * 40];
    for (int idx = threadIdx.x; idx < 2048; idx += 256) {
        int n = idx & 127, k = (idx >> 7) * 2;
        pack2(&Wt[n * 40 + k], W[k * HID + n], W[(k + 1) * HID + n]);
    }
    __syncthreads();

    const int lane = threadIdx.x & 63;
    const int wave = threadIdx.x >> 6;
    const int m16 = lane & 15, quad = lane >> 4;
    const int row0 = blockIdx.x * 64 + wave * 16;
    if (row0 >= N_NODES) return;

    int arow = row0 + m16; if (arow >= N_NODES) arow = N_NODES - 1;
    half8 a = *(const half8*)(z + (size_t)arow * IN_F + quad * 8);

    floatx4 acc[8];
#pragma unroll
    for (int t = 0; t < 8; ++t) acc[t] = (floatx4){0.f, 0.f, 0.f, 0.f};
#pragma unroll
    for (int t = 0; t < 8; ++t) {
        half8 b = *(const half8*)&Wt[(t * 16 + m16) * 40 + quad * 8];
        acc[t] = __builtin_amdgcn_mfma_f32_16x16x32_f16(a, b, acc[t], 0, 0, 0);
    }
#pragma unroll
    for (int t = 0; t < 8; ++t) {
        int c = t * 16 + m16;
        float bj = bias[c];
#pragma unroll
        for (int r = 0; r < 4; ++r) {
            int row = row0 + quad * 4 + r;
            if (row < N_NODES) {
                float v = acc[t][r] + bj;
                Hh[(size_t)row * HID + c] = (_Float16)(v > 0.f ? v : 0.f);
            }
        }
    }
}

__global__ __launch_bounds__(256) void k_xform2_mfma(
    const _Float16* __restrict__ H, const float* __restrict__ W,
    const int* __restrict__ ideg, _Float16* __restrict__ T) {
    __shared__ _Float16 Wt[128 * 136];
    for (int idx = threadIdx.x; idx < 8192; idx += 256) {
        int n = idx & 127, k = (idx >> 7) * 2;
        pack2(&Wt[n * 136 + k], W[k * HID + n], W[(k + 1) * HID + n]);
    }
    __syncthreads();

    const int lane = threadIdx.x & 63;
    const int wave = threadIdx.x >> 6;
    const int m16 = lane & 15, quad = lane >> 4;
    const int row0 = blockIdx.x * 64 + wave * 16;
    if (row0 >= N_NODES) return;

    int arow = row0 + m16; if (arow >= N_NODES) arow = N_NODES - 1;
    const _Float16* hp = H + (size_t)arow * HID + quad * 8;
    half8 a[4];
#pragma unroll
    for (int kk = 0; kk < 4; ++kk) a[kk] = *(const half8*)(hp + kk * 32);

    floatx4 acc[8];
#pragma unroll
    for (int t = 0; t < 8; ++t) acc[t] = (floatx4){0.f, 0.f, 0.f, 0.f};
#pragma unroll
    for (int t = 0; t < 8; ++t) {
        const _Float16* wp = &Wt[(t * 16 + m16) * 136 + quad * 8];
#pragma unroll
        for (int kk = 0; kk < 4; ++kk) {
            half8 b = *(const half8*)(wp + kk * 32);
            acc[t] = __builtin_amdgcn_mfma_f32_16x16x32_f16(a[kk], b, acc[t], 0, 0, 0);
        }
    }
    float dis[4];
#pragma unroll
    for (int r = 0; r < 4; ++r) {
        int row = row0 + quad * 4 + r;
        dis[r] = (row < N_NODES) ? rsqrtf(1.0f + (float)ideg[row]) : 0.f;
    }
#pragma unroll
    for (int t = 0; t < 8; ++t) {
        int c = t * 16 + m16;
#pragma unroll
        for (int r = 0; r < 4; ++r) {
            int row = row0 + quad * 4 + r;
            if (row < N_NODES)
                T[(size_t)row * HID + c] = (_Float16)(acc[t][r] * dis[r]);
        }
    }
}

__global__ __launch_bounds__(256) void k_xform3_mfma(
    const _Float16* __restrict__ H, const float* __restrict__ W,
    const int* __restrict__ ideg, _Float16* __restrict__ T) {
    __shared__ _Float16 Wt[32 * 136];
    for (int idx = threadIdx.x; idx < 2048; idx += 256) {
        int n = idx & 31, k = (idx >> 5) * 2;
        pack2(&Wt[n * 136 + k], W[k * IN_F + n], W[(k + 1) * IN_F + n]);
    }
    __syncthreads();

    const int lane = threadIdx.x & 63;
    const int wave = threadIdx.x >> 6;
    const int m16 = lane & 15, quad = lane >> 4;
    const int row0 = blockIdx.x * 64 + wave * 16;
    if (row0 >= N_NODES) return;

    int arow = row0 + m16; if (arow >= N_NODES) arow = N_NODES - 1;
    const _Float16* hp = H + (size_t)arow * HID + quad * 8;
    half8 a[4];
#pragma unroll
    for (int kk = 0; kk < 4; ++kk) a[kk] = *(const half8*)(hp + kk * 32);

    floatx4 acc[2];
#pragma unroll
    for (int t = 0; t < 2; ++t) acc[t] = (floatx4){0.f, 0.f, 0.f, 0.f};
#pragma unroll
    for (int t = 0; t < 2; ++t) {
        const _Float16* wp = &Wt[(t * 16 + m16) * 136 + quad * 8];
#pragma unroll
        for (int kk = 0; kk < 4; ++kk) {
            half8 b = *(const half8*)(wp + kk * 32);
            acc[t] = __builtin_amdgcn_mfma_f32_16x16x32_f16(a[kk], b, acc[t], 0, 0, 0);
        }
    }
    float dis[4];
#pragma unroll
    for (int r = 0; r < 4; ++r) {
        int row = row0 + quad * 4 + r;
        dis[r] = (row < N_NODES) ? rsqrtf(1.0f + (float)ideg[row]) : 0.f;
    }
#pragma unroll
    for (int t = 0; t < 2; ++t) {
        int c = t * 16 + m16;
#pragma unroll
        for (int r = 0; r < 4; ++r) {
            int row = row0 + quad * 4 + r;
            if (row < N_NODES)
                T[(size_t)row * IN_F + c] = (_Float16)(acc[t][r] * dis[r]);
        }
    }
}

// ---------------- launch ----------------

extern "C" void kernel_launch(void* const* d_in, const int* in_sizes, int n_in,
                              void* d_out, int out_size, void* d_ws, size_t ws_size,
                              hipStream_t stream) {
    const float* x  = (const float*)d_in[0];
    const int*   ei = (const int*)d_in[1];
    const float* W1 = (const float*)d_in[2];
    const float* b1 = (const float*)d_in[3];
    const float* W2 = (const float*)d_in[4];
    const float* b2 = (const float*)d_in[5];
    const float* W3 = (const float*)d_in[6];
    const float* b3 = (const float*)d_in[7];
    float* out = (float*)d_out;

    const int* src = ei;             // edge_index[0]
    const int* dst = ei + N_EDGES;   // edge_index[1]

    // workspace layout (all offsets 16B-aligned)
    int*      ideg   = (int*)d_ws;                           // N (padded 102400)
    int*      cursor = ideg + 102400;                        // N
    int*      bcnt   = cursor + 102400;                      // 256
    int*      bbase  = bcnt + 256;                           // 256 (197 used)
    int*      bcur   = bbase + 256;                          // 256
    int*      col    = bcur + 256;                           // E
    unsigned* rec    = (unsigned*)(col + N_EDGES);           // E
    _Float16* t1h    = (_Float16*)(rec + N_EDGES);           // N*32 fp16 (L1 msgs)
    _Float16* z      = t1h + (size_t)N_NODES * IN_F;         // N*32 fp16
    _Float16* H1h    = z + (size_t)N_NODES * IN_F;           // N*128 fp16
    _Float16* T2h    = H1h + (size_t)N_NODES * HID;          // N*128 fp16 (reused as T3)
    _Float16* H2h    = T2h + (size_t)N_NODES * HID;          // N*128 fp16

    const int xgrid = (N_NODES + 63) / 64;   // 1563

    // ---- CSR build + fused prescale ----
    hipMemsetAsync(bcnt, 0, 256 * sizeof(int), stream);
    k_bcount<<<NBB, 256, 0, stream>>>(dst, bcnt);
    k_bscan<<<1, 256, 0, stream>>>(bcnt, bbase, bcur);
    k_bucket<<<NBB, 256, 0, stream>>>(src, dst, bcur, rec);
    k_fill3p<<<NBUCK, 256, 0, stream>>>(rec, bbase, (const float2*)x,
                                        ideg, cursor, col, (__half2*)t1h);

    // ---- layer 1 (aggregate-first; 32-dim gather, then MFMA 32->128) ----
    k_gather32_pre<<<2048, 256, 0, stream>>>(cursor, ideg, col, t1h, z);
    k_xform1_mfma<<<xgrid, 256, 0, stream>>>(z, W1, b1, H1h);

    // ---- layer 2 (MFMA 128->128, then 128-dim fp16 gather) ----
    k_xform2_mfma<<<xgrid, 256, 0, stream>>>(H1h, W2, ideg, T2h);
    k_gather128<<<2048, 256, 0, stream>>>(cursor, ideg, col, T2h, b2, H2h);

    // ---- layer 3 (MFMA 128->32, then 32-dim fp16 gather) ----
    k_xform3_mfma<<<xgrid, 256, 0, stream>>>(H2h, W3, ideg, T2h);
    k_gather32_fin<<<2048, 256, 0, stream>>>(cursor, ideg, col, T2h, b3, out);
}

// Round 14
// 332.274 us; speedup vs baseline: 1.0631x; 1.0302x over previous
//
#include <hip/hip_runtime.h>
#include <hip/hip_fp16.h>

#define N_NODES 100000
#define N_EDGES 1600000
#define IN_F 32
#define HID 128
#define BSHIFT 9
#define BSIZE 512
#define NBUCK 196       // ceil(100000/512)
#define EPB 8192        // edges per bucket-phase block
#define NBB 196         // ceil(E/EPB)

typedef _Float16 half8 __attribute__((ext_vector_type(8)));
typedef float floatx4 __attribute__((ext_vector_type(4)));

static __device__ __forceinline__ void pack2(_Float16* dst, float a, float b) {
    union { _Float16 h[2]; unsigned u; } p;
    p.h[0] = (_Float16)a; p.h[1] = (_Float16)b;
    *(unsigned*)dst = p.u;
}

// ---------------- CSR build (bucketed, no global per-node atomics) ----------------

__global__ __launch_bounds__(256) void k_bcount(const int* __restrict__ dst,
                                                int* __restrict__ bcnt) {
    __shared__ int hist[256];
    hist[threadIdx.x] = 0;
    __syncthreads();
    const int e0 = blockIdx.x * EPB;
#pragma unroll 4
    for (int k = 0; k < 32; ++k) {
        int e = e0 + k * 256 + threadIdx.x;
        if (e < N_EDGES) atomicAdd(&hist[dst[e] >> BSHIFT], 1);
    }
    __syncthreads();
    int c = hist[threadIdx.x];
    if (c > 0) atomicAdd(&bcnt[threadIdx.x], c);
}

__global__ __launch_bounds__(256) void k_bscan(const int* __restrict__ bcnt,
                                               int* __restrict__ bbase,
                                               int* __restrict__ bcur) {
    __shared__ int s[256];
    int v = (threadIdx.x < NBUCK) ? bcnt[threadIdx.x] : 0;
    s[threadIdx.x] = v;
    __syncthreads();
    for (int off = 1; off < 256; off <<= 1) {
        int t = (threadIdx.x >= off) ? s[threadIdx.x - off] : 0;
        __syncthreads();
        s[threadIdx.x] += t;
        __syncthreads();
    }
    if (threadIdx.x < NBUCK) {
        int ex = s[threadIdx.x] - v;
        bbase[threadIdx.x] = ex;
        bcur[threadIdx.x]  = ex;
    }
    if (threadIdx.x == 0) bbase[NBUCK] = N_EDGES;
}

__global__ __launch_bounds__(256) void k_bucket(const int* __restrict__ src,
                                                const int* __restrict__ dst,
                                                int* __restrict__ bcur,
                                                unsigned* __restrict__ rec) {
    __shared__ int hist[256];
    __shared__ int lbase[256];
    const int e0 = blockIdx.x * EPB;
    hist[threadIdx.x] = 0;
    __syncthreads();

    unsigned rk[32]; short bk[32];
#pragma unroll
    for (int k = 0; k < 32; ++k) {
        int e = e0 + k * 256 + threadIdx.x;
        if (e < N_EDGES) {
            int d = dst[e];
            int b = d >> BSHIFT;
            bk[k] = (short)b;
            rk[k] = ((unsigned)src[e] << BSHIFT) | (unsigned)(d & (BSIZE - 1));
            atomicAdd(&hist[b], 1);
        } else bk[k] = -1;
    }
    __syncthreads();
    int c = hist[threadIdx.x];
    lbase[threadIdx.x] = (c > 0) ? atomicAdd(&bcur[threadIdx.x], c) : 0;
    __syncthreads();
    hist[threadIdx.x] = 0;   // reuse as local running offset
    __syncthreads();
#pragma unroll
    for (int k = 0; k < 32; ++k) {
        if (bk[k] >= 0) {
            int off = atomicAdd(&hist[bk[k]], 1);
            rec[lbase[bk[k]] + off] = rk[k];
        }
    }
}

// per bucket: LDS degree count + LDS scan -> ideg/cursor (coalesced) + col scatter
__global__ __launch_bounds__(256) void k_fill3(const unsigned* __restrict__ rec,
                                               const int* __restrict__ bbase,
                                               int* __restrict__ ideg,
                                               int* __restrict__ cursor,
                                               int* __restrict__ col) {
    __shared__ int lcnt[BSIZE];
    __shared__ int lcur[BSIZE];
    __shared__ int s[256];
    const int b = blockIdx.x;
    const int n0 = b << BSHIFT;
    const int rbeg = bbase[b];
    const int rend = bbase[b + 1];

    lcnt[threadIdx.x] = 0;
    lcnt[threadIdx.x + 256] = 0;
    __syncthreads();
    for (int i = rbeg + threadIdx.x; i < rend; i += 256)
        atomicAdd(&lcnt[rec[i] & (BSIZE - 1)], 1);
    __syncthreads();

    int a0 = lcnt[2 * threadIdx.x], a1 = lcnt[2 * threadIdx.x + 1];
    int pv = a0 + a1;
    s[threadIdx.x] = pv;
    __syncthreads();
    for (int off = 1; off < 256; off <<= 1) {
        int t = (threadIdx.x >= off) ? s[threadIdx.x - off] : 0;
        __syncthreads();
        s[threadIdx.x] += t;
        __syncthreads();
    }
    int ex = s[threadIdx.x] - pv;            // exclusive over pairs
    lcur[2 * threadIdx.x]     = rbeg + ex;
    lcur[2 * threadIdx.x + 1] = rbeg + ex + a0;
    __syncthreads();

    for (int t = threadIdx.x; t < BSIZE; t += 256) {
        int n = n0 + t;
        if (n < N_NODES) {
            ideg[n]   = lcnt[t];
            cursor[n] = lcur[t];
        }
    }
    __syncthreads();
    for (int i = rbeg + threadIdx.x; i < rend; i += 256) {
        unsigned r = rec[i];
        int slot = atomicAdd(&lcur[r & (BSIZE - 1)], 1);
        col[slot] = (int)(r >> BSHIFT);
    }
}

// ---------------- layer-1 prescale: t1 = x * dis (fp16, 32-dim) ----------------

__global__ void k_prescale(const float2* __restrict__ x, const int* __restrict__ ideg,
                           __half2* __restrict__ T) {
    int tid = blockIdx.x * 256 + threadIdx.x;
    if (tid >= N_NODES * 16) return;
    int i = tid >> 4;
    float dis = rsqrtf(1.0f + (float)ideg[i]);
    float2 v = x[tid];
    T[tid] = __floats2half2_rn(v.x * dis, v.y * dis);
}

// ---------------- gathers (r9-proven v2 loops) ----------------

// pre: z = acc*dis, fp16 out. 16 slots x 4 feat-lanes.
__global__ __launch_bounds__(256) void k_gather32_pre(
    const int* __restrict__ cursor, const int* __restrict__ ideg,
    const int* __restrict__ col, const _Float16* __restrict__ T,
    _Float16* __restrict__ OUT) {
    const int lane = threadIdx.x & 63;
    const int slot = lane >> 2;
    const int fl   = lane & 3;
    const int wid  = blockIdx.x * 4 + (threadIdx.x >> 6);
    const int wstride = gridDim.x * 4;

    for (int node = wid; node < N_NODES; node += wstride) {
        int begin = cursor[node];
        int d     = ideg[node];
        int end   = begin + d;
        float acc[8];
        if (slot == 0) {
            half8 v = *(const half8*)(T + (size_t)node * IN_F + fl * 8);
#pragma unroll
            for (int i = 0; i < 8; ++i) acc[i] = (float)v[i];
        } else {
#pragma unroll
            for (int i = 0; i < 8; ++i) acc[i] = 0.f;
        }
        for (int e = begin; e < end; e += 16) {
            int ee = e + slot;
            if (ee < end) {
                int s = col[ee];
                half8 v = *(const half8*)(T + (size_t)s * IN_F + fl * 8);
#pragma unroll
                for (int i = 0; i < 8; ++i) acc[i] += (float)v[i];
            }
        }
#pragma unroll
        for (int m = 4; m < 64; m <<= 1)
#pragma unroll
            for (int i = 0; i < 8; ++i) acc[i] += __shfl_xor(acc[i], m, 64);
        if (slot == 0) {
            float dis = rsqrtf(1.0f + (float)d);
            half8 o;
#pragma unroll
            for (int i = 0; i < 8; ++i) o[i] = (_Float16)(acc[i] * dis);
            *(half8*)(OUT + (size_t)node * IN_F + fl * 8) = o;
        }
    }
}

// fin: out = relu(acc*dis + b), fp32 out
__global__ __launch_bounds__(256) void k_gather32_fin(
    const int* __restrict__ cursor, const int* __restrict__ ideg,
    const int* __restrict__ col, const _Float16* __restrict__ T,
    const float* __restrict__ b, float* __restrict__ OUT) {
    const int lane = threadIdx.x & 63;
    const int slot = lane >> 2;
    const int fl   = lane & 3;
    const int wid  = blockIdx.x * 4 + (threadIdx.x >> 6);
    const int wstride = gridDim.x * 4;

    float4 bb0 = *(const float4*)(b + fl * 8);
    float4 bb1 = *(const float4*)(b + fl * 8 + 4);
    float bias[8] = {bb0.x, bb0.y, bb0.z, bb0.w, bb1.x, bb1.y, bb1.z, bb1.w};

    for (int node = wid; node < N_NODES; node += wstride) {
        int begin = cursor[node];
        int d     = ideg[node];
        int end   = begin + d;
        float acc[8];
        if (slot == 0) {
            half8 v = *(const half8*)(T + (size_t)node * IN_F + fl * 8);
#pragma unroll
            for (int i = 0; i < 8; ++i) acc[i] = (float)v[i];
        } else {
#pragma unroll
            for (int i = 0; i < 8; ++i) acc[i] = 0.f;
        }
        for (int e = begin; e < end; e += 16) {
            int ee = e + slot;
            if (ee < end) {
                int s = col[ee];
                half8 v = *(const half8*)(T + (size_t)s * IN_F + fl * 8);
#pragma unroll
                for (int i = 0; i < 8; ++i) acc[i] += (float)v[i];
            }
        }
#pragma unroll
        for (int m = 4; m < 64; m <<= 1)
#pragma unroll
            for (int i = 0; i < 8; ++i) acc[i] += __shfl_xor(acc[i], m, 64);
        if (slot == 0) {
            float dis = rsqrtf(1.0f + (float)d);
            float o[8];
#pragma unroll
            for (int i = 0; i < 8; ++i) {
                float v = acc[i] * dis + bias[i];
                o[i] = v > 0.f ? v : 0.f;
            }
            float* op = OUT + (size_t)node * IN_F + fl * 8;
            *(float4*)op       = make_float4(o[0], o[1], o[2], o[3]);
            *(float4*)(op + 4) = make_float4(o[4], o[5], o[6], o[7]);
        }
    }
}

// 128-dim: 4 slots x 16 feat-lanes, x2 unroll; fp16 out = relu(acc*dis+b)
__global__ __launch_bounds__(256) void k_gather128(
    const int* __restrict__ cursor, const int* __restrict__ ideg,
    const int* __restrict__ col, const _Float16* __restrict__ T,
    const float* __restrict__ b, _Float16* __restrict__ OUT) {
    const int lane = threadIdx.x & 63;
    const int slot = lane >> 4;
    const int fl   = lane & 15;
    const int wid  = blockIdx.x * 4 + (threadIdx.x >> 6);
    const int wstride = gridDim.x * 4;

    float4 bb0 = *(const float4*)(b + fl * 8);
    float4 bb1 = *(const float4*)(b + fl * 8 + 4);
    float bias[8] = {bb0.x, bb0.y, bb0.z, bb0.w, bb1.x, bb1.y, bb1.z, bb1.w};

    for (int node = wid; node < N_NODES; node += wstride) {
        int begin = cursor[node];
        int d     = ideg[node];
        int end   = begin + d;
        float acc[8];
        if (slot == 0) {
            half8 v = *(const half8*)(T + (size_t)node * HID + fl * 8);
#pragma unroll
            for (int i = 0; i < 8; ++i) acc[i] = (float)v[i];
        } else {
#pragma unroll
            for (int i = 0; i < 8; ++i) acc[i] = 0.f;
        }
        for (int e = begin; e < end; e += 8) {
            int ee0 = e + slot;
            int ee1 = e + 4 + slot;
            if (ee1 < end) {
                int s0 = col[ee0];
                int s1 = col[ee1];
                half8 v0 = *(const half8*)(T + (size_t)s0 * HID + fl * 8);
                half8 v1 = *(const half8*)(T + (size_t)s1 * HID + fl * 8);
#pragma unroll
                for (int i = 0; i < 8; ++i) acc[i] += (float)v0[i] + (float)v1[i];
            } else if (ee0 < end) {
                int s0 = col[ee0];
                half8 v0 = *(const half8*)(T + (size_t)s0 * HID + fl * 8);
#pragma unroll
                for (int i = 0; i < 8; ++i) acc[i] += (float)v0[i];
            }
        }
#pragma unroll
        for (int m = 16; m < 64; m <<= 1)
#pragma unroll
            for (int i = 0; i < 8; ++i) acc[i] += __shfl_xor(acc[i], m, 64);
        if (slot == 0) {
            float dis = rsqrtf(1.0f + (float)d);
            half8 o;
#pragma unroll
            for (int i = 0; i < 8; ++i) {
                float v = acc[i] * dis + bias[i];
                o[i] = (_Float16)(v > 0.f ? v : 0.f);
            }
            *(half8*)(OUT + (size_t)node * HID + fl * 8) = o;
        }
    }
}

// ---------------- MFMA transforms (r9-proven) ----------------
// 16x16x32 layouts: A[m=lane&15][k=quad*8+j], B[k=quad*8+j][n=lane&15],
// D[row=quad*4+r][col=lane&15]. Block = 4 waves x 16 rows = 64 rows.

__global__ __launch_bounds__(256) void k_xform1_mfma(
    const _Float16* __restrict__ z, const float* __restrict__ W,
    const float* __restrict__ bias, _Float16* __restrict__ Hh) {
    __shared__ _Float16 Wt[128 * 40];
    for (int idx = threadIdx.x; idx < 2048; idx += 256) {
        int n = idx & 127, k = (idx >> 7) * 2;
        pack2(&Wt[n * 40 + k], W[k * HID + n], W[(k + 1) * HID + n]);
    }
    __syncthreads();

    const int lane = threadIdx.x & 63;
    const int wave = threadIdx.x >> 6;
    const int m16 = lane & 15, quad = lane >> 4;
    const int row0 = blockIdx.x * 64 + wave * 16;
    if (row0 >= N_NODES) return;

    int arow = row0 + m16; if (arow >= N_NODES) arow = N_NODES - 1;
    half8 a = *(const half8*)(z + (size_t)arow * IN_F + quad * 8);

    floatx4 acc[8];
#pragma unroll
    for (int t = 0; t < 8; ++t) acc[t] = (floatx4){0.f, 0.f, 0.f, 0.f};
#pragma unroll
    for (int t = 0; t < 8; ++t) {
        half8 b = *(const half8*)&Wt[(t * 16 + m16) * 40 + quad * 8];
        acc[t] = __builtin_amdgcn_mfma_f32_16x16x32_f16(a, b, acc[t], 0, 0, 0);
    }
#pragma unroll
    for (int t = 0; t < 8; ++t) {
        int c = t * 16 + m16;
        float bj = bias[c];
#pragma unroll
        for (int r = 0; r < 4; ++r) {
            int row = row0 + quad * 4 + r;
            if (row < N_NODES) {
                float v = acc[t][r] + bj;
                Hh[(size_t)row * HID + c] = (_Float16)(v > 0.f ? v : 0.f);
            }
        }
    }
}

__global__ __launch_bounds__(256) void k_xform2_mfma(
    const _Float16* __restrict__ H, const float* __restrict__ W,
    const int* __restrict__ ideg, _Float16* __restrict__ T) {
    __shared__ _Float16 Wt[128 * 136];
    for (int idx = threadIdx.x; idx < 8192; idx += 256) {
        int n = idx & 127, k = (idx >> 7) * 2;
        pack2(&Wt[n * 136 + k], W[k * HID + n], W[(k + 1) * HID + n]);
    }
    __syncthreads();

    const int lane = threadIdx.x & 63;
    const int wave = threadIdx.x >> 6;
    const int m16 = lane & 15, quad = lane >> 4;
    const int row0 = blockIdx.x * 64 + wave * 16;
    if (row0 >= N_NODES) return;

    int arow = row0 + m16; if (arow >= N_NODES) arow = N_NODES - 1;
    const _Float16* hp = H + (size_t)arow * HID + quad * 8;
    half8 a[4];
#pragma unroll
    for (int kk = 0; kk < 4; ++kk) a[kk] = *(const half8*)(hp + kk * 32);

    floatx4 acc[8];
#pragma unroll
    for (int t = 0; t < 8; ++t) acc[t] = (floatx4){0.f, 0.f, 0.f, 0.f};
#pragma unroll
    for (int t = 0; t < 8; ++t) {
        const _Float16* wp = &Wt[(t * 16 + m16) * 136 + quad * 8];
#pragma unroll
        for (int kk = 0; kk < 4; ++kk) {
            half8 b = *(const half8*)(wp + kk * 32);
            acc[t] = __builtin_amdgcn_mfma_f32_16x16x32_f16(a[kk], b, acc[t], 0, 0, 0);
        }
    }
    float dis[4];
#pragma unroll
    for (int r = 0; r < 4; ++r) {
        int row = row0 + quad * 4 + r;
        dis[r] = (row < N_NODES) ? rsqrtf(1.0f + (float)ideg[row]) : 0.f;
    }
#pragma unroll
    for (int t = 0; t < 8; ++t) {
        int c = t * 16 + m16;
#pragma unroll
        for (int r = 0; r < 4; ++r) {
            int row = row0 + quad * 4 + r;
            if (row < N_NODES)
                T[(size_t)row * HID + c] = (_Float16)(acc[t][r] * dis[r]);
        }
    }
}

__global__ __launch_bounds__(256) void k_xform3_mfma(
    const _Float16* __restrict__ H, const float* __restrict__ W,
    const int* __restrict__ ideg, _Float16* __restrict__ T) {
    __shared__ _Float16 Wt[32 * 136];
    for (int idx = threadIdx.x; idx < 2048; idx += 256) {
        int n = idx & 31, k = (idx >> 5) * 2;
        pack2(&Wt[n * 136 + k], W[k * IN_F + n], W[(k + 1) * IN_F + n]);
    }
    __syncthreads();

    const int lane = threadIdx.x & 63;
    const int wave = threadIdx.x >> 6;
    const int m16 = lane & 15, quad = lane >> 4;
    const int row0 = blockIdx.x * 64 + wave * 16;
    if (row0 >= N_NODES) return;

    int arow = row0 + m16; if (arow >= N_NODES) arow = N_NODES - 1;
    const _Float16* hp = H + (size_t)arow * HID + quad * 8;
    half8 a[4];
#pragma unroll
    for (int kk = 0; kk < 4; ++kk) a[kk] = *(const half8*)(hp + kk * 32);

    floatx4 acc[2];
#pragma unroll
    for (int t = 0; t < 2; ++t) acc[t] = (floatx4){0.f, 0.f, 0.f, 0.f};
#pragma unroll
    for (int t = 0; t < 2; ++t) {
        const _Float16* wp = &Wt[(t * 16 + m16) * 136 + quad * 8];
#pragma unroll
        for (int kk = 0; kk < 4; ++kk) {
            half8 b = *(const half8*)(wp + kk * 32);
            acc[t] = __builtin_amdgcn_mfma_f32_16x16x32_f16(a[kk], b, acc[t], 0, 0, 0);
        }
    }
    float dis[4];
#pragma unroll
    for (int r = 0; r < 4; ++r) {
        int row = row0 + quad * 4 + r;
        dis[r] = (row < N_NODES) ? rsqrtf(1.0f + (float)ideg[row]) : 0.f;
    }
#pragma unroll
    for (int t = 0; t < 2; ++t) {
        int c = t * 16 + m16;
#pragma unroll
        for (int r = 0; r < 4; ++r) {
            int row = row0 + quad * 4 + r;
            if (row < N_NODES)
                T[(size_t)row * IN_F + c] = (_Float16)(acc[t][r] * dis[r]);
        }
    }
}

// ---------------- launch ----------------

extern "C" void kernel_launch(void* const* d_in, const int* in_sizes, int n_in,
                              void* d_out, int out_size, void* d_ws, size_t ws_size,
                              hipStream_t stream) {
    const float* x  = (const float*)d_in[0];
    const int*   ei = (const int*)d_in[1];
    const float* W1 = (const float*)d_in[2];
    const float* b1 = (const float*)d_in[3];
    const float* W2 = (const float*)d_in[4];
    const float* b2 = (const float*)d_in[5];
    const float* W3 = (const float*)d_in[6];
    const float* b3 = (const float*)d_in[7];
    float* out = (float*)d_out;

    const int* src = ei;             // edge_index[0]
    const int* dst = ei + N_EDGES;   // edge_index[1]

    // workspace layout (all offsets 16B-aligned)
    int*      ideg   = (int*)d_ws;                           // N (padded 102400)
    int*      cursor = ideg + 102400;                        // N
    int*      bcnt   = cursor + 102400;                      // 256
    int*      bbase  = bcnt + 256;                           // 256 (197 used)
    int*      bcur   = bbase + 256;                          // 256
    int*      col    = bcur + 256;                           // E
    unsigned* rec    = (unsigned*)(col + N_EDGES);           // E
    _Float16* t1h    = (_Float16*)(rec + N_EDGES);           // N*32 fp16 (L1 msgs)
    _Float16* z      = t1h + (size_t)N_NODES * IN_F;         // N*32 fp16
    _Float16* H1h    = z + (size_t)N_NODES * IN_F;           // N*128 fp16
    _Float16* T2h    = H1h + (size_t)N_NODES * HID;          // N*128 fp16 (reused as T3)
    _Float16* H2h    = T2h + (size_t)N_NODES * HID;          // N*128 fp16

    const int xgrid = (N_NODES + 63) / 64;   // 1563

    // ---- CSR build (bucketed; no global per-node atomics) ----
    hipMemsetAsync(bcnt, 0, 256 * sizeof(int), stream);
    k_bcount<<<NBB, 256, 0, stream>>>(dst, bcnt);
    k_bscan<<<1, 256, 0, stream>>>(bcnt, bbase, bcur);
    k_bucket<<<NBB, 256, 0, stream>>>(src, dst, bcur, rec);
    k_fill3<<<NBUCK, 256, 0, stream>>>(rec, bbase, ideg, cursor, col);

    // ---- layer 1 (aggregate-first; 32-dim gather, then MFMA 32->128) ----
    k_prescale<<<(N_NODES * 16 + 255) / 256, 256, 0, stream>>>(
        (const float2*)x, ideg, (__half2*)t1h);
    k_gather32_pre<<<2048, 256, 0, stream>>>(cursor, ideg, col, t1h, z);
    k_xform1_mfma<<<xgrid, 256, 0, stream>>>(z, W1, b1, H1h);

    // ---- layer 2 (MFMA 128->128, then 128-dim fp16 gather) ----
    k_xform2_mfma<<<xgrid, 256, 0, stream>>>(H1h, W2, ideg, T2h);
    k_gather128<<<2048, 256, 0, stream>>>(cursor, ideg, col, T2h, b2, H2h);

    // ---- layer 3 (MFMA 128->32, then 32-dim fp16 gather) ----
    k_xform3_mfma<<<xgrid, 256, 0, stream>>>(H2h, W3, ideg, T2h);
    k_gather32_fin<<<2048, 256, 0, stream>>>(cursor, ideg, col, T2h, b3, out);
}